// Round 1
// baseline (1112.438 us; speedup 1.0000x reference)
//
#include <hip/hip_runtime.h>
#include <hip/hip_bf16.h>
#include <math.h>

#define GS_N 4096
#define IMG_H 96
#define IMG_W 96
#define NPIX (IMG_H * IMG_W)

// SH constants
#define SH_C0 0.28209479177387814f
#define SH_C1 0.4886025119029199f
__device__ __constant__ float kC2[5] = {1.0925484305920792f, -1.0925484305920792f, 0.31539156525252005f, -1.0925484305920792f, 0.5462742152960396f};
__device__ __constant__ float kC3[7] = {-0.5900435899266435f, 2.890611442640554f, -0.4570457994644658f, 0.3731763325901154f, -0.4570457994644658f, 1.445305721320277f, -0.5900435899266435f};

// -------------------- Kernel 1: per-gaussian preprocessing --------------------
__global__ __launch_bounds__(256) void gs_prep(
    const float* __restrict__ pws, const float* __restrict__ low_shs,
    const float* __restrict__ high_shs, const float* __restrict__ alphas_raw,
    const float* __restrict__ scales_raw, const float* __restrict__ rots_raw,
    const float* __restrict__ Rcw, const float* __restrict__ tcw,
    const float* __restrict__ cam,
    float* __restrict__ areas_out,      // N*2, original order (part of d_out)
    float* __restrict__ depth_ws,       // N
    float4* __restrict__ A_uns,         // {ux, uy, ci0, ci1}
    float4* __restrict__ B_uns,         // {ci2, alpha_eff, colR, colG}
    float* __restrict__ C_uns)          // colB
{
    int i = blockIdx.x * 256 + threadIdx.x;
    if (i >= GS_N) return;

    float fx = cam[0], fy = cam[1], cxi = cam[2], cyi = cam[3];
    float R0 = Rcw[0], R1 = Rcw[1], R2 = Rcw[2];
    float R3 = Rcw[3], R4 = Rcw[4], R5 = Rcw[5];
    float R6 = Rcw[6], R7 = Rcw[7], R8 = Rcw[8];
    float t0 = tcw[0], t1 = tcw[1], t2 = tcw[2];

    float pwx = pws[3*i+0], pwy = pws[3*i+1], pwz = pws[3*i+2];

    // camera-space point: pcs = Rcw @ pw + tcw
    float pcx = R0*pwx + R1*pwy + R2*pwz + t0;
    float pcy = R3*pwx + R4*pwy + R5*pwz + t1;
    float pcz = R6*pwx + R7*pwy + R8*pwz + t2;

    float depth = pcz;
    float zs = (depth > 1e-6f) ? depth : 1e-6f;

    float ux = fx * pcx / zs + cxi;
    float uy = fy * pcy / zs + cyi;

    float alpha = 1.0f / (1.0f + expf(-alphas_raw[i]));

    float s0 = expf(scales_raw[3*i+0]);
    float s1 = expf(scales_raw[3*i+1]);
    float s2 = expf(scales_raw[3*i+2]);

    float qw = rots_raw[4*i+0], qx = rots_raw[4*i+1], qy = rots_raw[4*i+2], qz = rots_raw[4*i+3];
    float qn = sqrtf(qw*qw + qx*qx + qy*qy + qz*qz);
    qw /= qn; qx /= qn; qy /= qn; qz /= qn;

    float r00 = 1.0f - 2.0f*(qy*qy + qz*qz);
    float r01 = 2.0f*(qx*qy - qw*qz);
    float r02 = 2.0f*(qx*qz + qw*qy);
    float r10 = 2.0f*(qx*qy + qw*qz);
    float r11 = 1.0f - 2.0f*(qx*qx + qz*qz);
    float r12 = 2.0f*(qy*qz - qw*qx);
    float r20 = 2.0f*(qx*qz - qw*qy);
    float r21 = 2.0f*(qy*qz + qw*qx);
    float r22 = 1.0f - 2.0f*(qx*qx + qy*qy);

    // M = Rot * diag(scale)
    float m00 = r00*s0, m01 = r01*s1, m02 = r02*s2;
    float m10 = r10*s0, m11 = r11*s1, m12 = r12*s2;
    float m20 = r20*s0, m21 = r21*s1, m22 = r22*s2;

    // cov3d = M M^T (symmetric)
    float V00 = m00*m00 + m01*m01 + m02*m02;
    float V01 = m00*m10 + m01*m11 + m02*m12;
    float V02 = m00*m20 + m01*m21 + m02*m22;
    float V11 = m10*m10 + m11*m11 + m12*m12;
    float V12 = m10*m20 + m11*m21 + m12*m22;
    float V22 = m20*m20 + m21*m21 + m22*m22;

    float limx = 1.3f * ((float)IMG_W / (2.0f * fx));
    float limy = 1.3f * ((float)IMG_H / (2.0f * fy));
    float xzr = pcx / zs, yzr = pcy / zs;
    float txv = fminf(fmaxf(xzr, -limx), limx) * zs;
    float tyv = fminf(fmaxf(yzr, -limy), limy) * zs;

    float J00 = fx / zs, J02 = -fx * txv / (zs * zs);
    float J11 = fy / zs, J12 = -fy * tyv / (zs * zs);

    // T = J @ Rcw  (2x3)
    float T00 = J00*R0 + J02*R6, T01 = J00*R1 + J02*R7, T02 = J00*R2 + J02*R8;
    float T10 = J11*R3 + J12*R6, T11 = J11*R4 + J12*R7, T12 = J11*R5 + J12*R8;

    // TW = T @ cov3d
    float TW00 = T00*V00 + T01*V01 + T02*V02;
    float TW01 = T00*V01 + T01*V11 + T02*V12;
    float TW02 = T00*V02 + T01*V12 + T02*V22;
    float TW10 = T10*V00 + T11*V01 + T12*V02;
    float TW11 = T10*V01 + T11*V11 + T12*V12;
    float TW12 = T10*V02 + T11*V12 + T12*V22;

    // cov2d = TW @ T^T
    float c00 = TW00*T00 + TW01*T01 + TW02*T02;
    float c01 = TW00*T10 + TW01*T11 + TW02*T12;
    float c11 = TW10*T10 + TW11*T11 + TW12*T12;

    float a  = c00 + 0.3f;
    float b  = c01;
    float cc = c11 + 0.3f;
    float det = a * cc - b * b;
    float ci0 = cc / det;
    float ci1 = -b / det;
    float ci2 = a / det;

    float mid = 0.5f * (a + cc);
    float lam = mid + sqrtf(fmaxf(mid * mid - det, 0.1f));
    float radius = ceilf(3.0f * sqrtf(lam));
    areas_out[2*i + 0] = radius;
    areas_out[2*i + 1] = radius;

    // view dir: twc = -(Rcw^T @ tcw)
    float twcx = -(R0*t0 + R3*t1 + R6*t2);
    float twcy = -(R1*t0 + R4*t1 + R7*t2);
    float twcz = -(R2*t0 + R5*t1 + R8*t2);
    float dx = pwx - twcx, dy = pwy - twcy, dz = pwz - twcz;
    float dn = sqrtf(dx*dx + dy*dy + dz*dz);
    dx /= dn; dy /= dn; dz /= dn;

    float xx = dx*dx, yy = dy*dy, zz = dz*dz;
    float xy = dx*dy, yz = dy*dz, xz = dx*dz;

    // SH basis (16)
    float bas0  = SH_C0;
    float bas1  = -SH_C1 * dy;
    float bas2  =  SH_C1 * dz;
    float bas3  = -SH_C1 * dx;
    float bas4  = kC2[0] * xy;
    float bas5  = kC2[1] * yz;
    float bas6  = kC2[2] * (2.0f*zz - xx - yy);
    float bas7  = kC2[3] * xz;
    float bas8  = kC2[4] * (xx - yy);
    float bas9  = kC3[0] * dy * (3.0f*xx - yy);
    float bas10 = kC3[1] * xy * dz;
    float bas11 = kC3[2] * dy * (4.0f*zz - xx - yy);
    float bas12 = kC3[3] * dz * (2.0f*zz - 3.0f*xx - 3.0f*yy);
    float bas13 = kC3[4] * dx * (4.0f*zz - xx - yy);
    float bas14 = kC3[5] * dz * (xx - yy);
    float bas15 = kC3[6] * dx * (xx - 3.0f*yy);

    float col[3];
    #pragma unroll
    for (int c = 0; c < 3; ++c) {
        const float* hs = high_shs + 45*i + c;
        float acc = bas0 * low_shs[3*i + c];
        acc += bas1  * hs[0*3];
        acc += bas2  * hs[1*3];
        acc += bas3  * hs[2*3];
        acc += bas4  * hs[3*3];
        acc += bas5  * hs[4*3];
        acc += bas6  * hs[5*3];
        acc += bas7  * hs[6*3];
        acc += bas8  * hs[7*3];
        acc += bas9  * hs[8*3];
        acc += bas10 * hs[9*3];
        acc += bas11 * hs[10*3];
        acc += bas12 * hs[11*3];
        acc += bas13 * hs[12*3];
        acc += bas14 * hs[13*3];
        acc += bas15 * hs[14*3];
        col[c] = fmaxf(acc + 0.5f, 0.0f);
    }

    bool valid = depth > 0.2f;
    float al_eff = valid ? alpha : 0.0f;   // alpha=0 => ap=0 => exact same as reference's masking

    depth_ws[i] = depth;
    A_uns[i] = make_float4(ux, uy, ci0, ci1);
    B_uns[i] = make_float4(ci2, al_eff, col[0], col[1]);
    C_uns[i] = col[2];
}

// -------------------- Kernel 2: O(N^2) stable rank sort + gather --------------------
__global__ __launch_bounds__(256) void gs_ranksort(
    const float* __restrict__ depth,
    const float4* __restrict__ A_uns, const float4* __restrict__ B_uns,
    const float* __restrict__ C_uns,
    float4* __restrict__ A_s, float4* __restrict__ B_s, float* __restrict__ C_s)
{
    __shared__ float sd[GS_N];
    int tid = threadIdx.x;
    int gid = blockIdx.x * 256 + tid;
    for (int j = tid; j < GS_N; j += 256) sd[j] = depth[j];
    __syncthreads();

    float mg = sd[gid];
    int rank = 0;
    const float4* s4 = (const float4*)sd;
    #pragma unroll 4
    for (int jj = 0; jj < GS_N/4; ++jj) {
        float4 v = s4[jj];
        int j0 = jj * 4;
        rank += (v.x < mg || (v.x == mg && (j0+0) < gid)) ? 1 : 0;
        rank += (v.y < mg || (v.y == mg && (j0+1) < gid)) ? 1 : 0;
        rank += (v.z < mg || (v.z == mg && (j0+2) < gid)) ? 1 : 0;
        rank += (v.w < mg || (v.w == mg && (j0+3) < gid)) ? 1 : 0;
    }
    A_s[rank] = A_uns[gid];
    B_s[rank] = B_uns[gid];
    C_s[rank] = C_uns[gid];
}

// -------------------- Kernel 3: per-pixel alpha compositing --------------------
__global__ __launch_bounds__(64) void gs_raster(
    const float4* __restrict__ A_s, const float4* __restrict__ B_s,
    const float* __restrict__ C_s, float* __restrict__ img)
{
    int p = blockIdx.x * 64 + threadIdx.x;
    float px = (float)(p % IMG_W);
    float py = (float)(p / IMG_W);

    float tau = 1.0f;
    float accr = 0.0f, accg = 0.0f, accb = 0.0f;

    for (int n = 0; n < GS_N; ++n) {
        float4 a4 = A_s[n];   // wave-uniform address -> scalar loads
        float4 b4 = B_s[n];
        float cb = C_s[n];

        float ddx = a4.x - px;
        float ddy = a4.y - py;
        float pw = -0.5f * (a4.z * ddx * ddx + b4.x * ddy * ddy) - a4.w * ddx * ddy;
        pw = fminf(pw, 0.0f);
        float ap = b4.y * __expf(pw);
        ap = fminf(ap, 0.99f);
        ap = (ap >= (1.0f / 255.0f)) ? ap : 0.0f;
        float wgt = (tau > 1e-4f) ? ap * tau : 0.0f;
        accr += b4.z * wgt;
        accg += b4.w * wgt;
        accb += cb * wgt;
        tau = tau * (1.0f - ap);
        // exact early exit: tau is monotone non-increasing; once <=1e-4 all
        // future wgt are identically 0 in the reference as well.
        if (__ballot(tau > 1e-4f) == 0) break;
    }

    img[0 * NPIX + p] = accr;
    img[1 * NPIX + p] = accg;
    img[2 * NPIX + p] = accb;
}

extern "C" void kernel_launch(void* const* d_in, const int* in_sizes, int n_in,
                              void* d_out, int out_size, void* d_ws, size_t ws_size,
                              hipStream_t stream) {
    const float* pws        = (const float*)d_in[0];
    const float* low_shs    = (const float*)d_in[1];
    const float* high_shs   = (const float*)d_in[2];
    const float* alphas_raw = (const float*)d_in[3];
    const float* scales_raw = (const float*)d_in[4];
    const float* rots_raw   = (const float*)d_in[5];
    // d_in[6] = us (unused by the forward pass)
    const float* Rcw        = (const float*)d_in[7];
    const float* tcw        = (const float*)d_in[8];
    const float* cam        = (const float*)d_in[9];

    float* out_img   = (float*)d_out;             // 3*96*96
    float* out_areas = (float*)d_out + 3 * NPIX;  // N*2

    // workspace layout (bytes)
    char* ws = (char*)d_ws;
    float*  depth_ws = (float*)(ws + 0);                    // N floats   (16 KB)
    float4* A_uns    = (float4*)(ws + 16384);               // N float4   (64 KB)
    float4* B_uns    = (float4*)(ws + 16384 + 65536);       // N float4
    float*  C_uns    = (float*)(ws + 16384 + 2*65536);      // N floats
    float4* A_s      = (float4*)(ws + 2*16384 + 2*65536);   // N float4
    float4* B_s      = (float4*)(ws + 2*16384 + 3*65536);   // N float4
    float*  C_s      = (float*)(ws + 2*16384 + 4*65536);    // N floats

    gs_prep<<<GS_N / 256, 256, 0, stream>>>(
        pws, low_shs, high_shs, alphas_raw, scales_raw, rots_raw, Rcw, tcw, cam,
        out_areas, depth_ws, A_uns, B_uns, C_uns);

    gs_ranksort<<<GS_N / 256, 256, 0, stream>>>(
        depth_ws, A_uns, B_uns, C_uns, A_s, B_s, C_s);

    gs_raster<<<NPIX / 64, 64, 0, stream>>>(A_s, B_s, C_s, out_img);
}

// Round 2
// 229.551 us; speedup vs baseline: 4.8461x; 4.8461x over previous
//
#include <hip/hip_runtime.h>
#include <hip/hip_bf16.h>
#include <math.h>

#define GS_N 4096
#define IMG_H 96
#define IMG_W 96
#define NPIX (IMG_H * IMG_W)

// SH constants
#define SH_C0 0.28209479177387814f
#define SH_C1 0.4886025119029199f
__device__ __constant__ float kC2[5] = {1.0925484305920792f, -1.0925484305920792f, 0.31539156525252005f, -1.0925484305920792f, 0.5462742152960396f};
__device__ __constant__ float kC3[7] = {-0.5900435899266435f, 2.890611442640554f, -0.4570457994644658f, 0.3731763325901154f, -0.4570457994644658f, 1.445305721320277f, -0.5900435899266435f};

// -------------------- Kernel 1: per-gaussian preprocessing --------------------
__global__ __launch_bounds__(256) void gs_prep(
    const float* __restrict__ pws, const float* __restrict__ low_shs,
    const float* __restrict__ high_shs, const float* __restrict__ alphas_raw,
    const float* __restrict__ scales_raw, const float* __restrict__ rots_raw,
    const float* __restrict__ Rcw, const float* __restrict__ tcw,
    const float* __restrict__ cam,
    float* __restrict__ areas_out,      // N*2, original order (part of d_out)
    float* __restrict__ depth_ws,       // N
    float4* __restrict__ A_uns,         // {ux, uy, ci0, ci1}
    float4* __restrict__ B_uns,         // {ci2, alpha_eff, colR, colG}
    float* __restrict__ C_uns)          // colB
{
    int i = blockIdx.x * 256 + threadIdx.x;
    if (i >= GS_N) return;

    float fx = cam[0], fy = cam[1], cxi = cam[2], cyi = cam[3];
    float R0 = Rcw[0], R1 = Rcw[1], R2 = Rcw[2];
    float R3 = Rcw[3], R4 = Rcw[4], R5 = Rcw[5];
    float R6 = Rcw[6], R7 = Rcw[7], R8 = Rcw[8];
    float t0 = tcw[0], t1 = tcw[1], t2 = tcw[2];

    float pwx = pws[3*i+0], pwy = pws[3*i+1], pwz = pws[3*i+2];

    // camera-space point: pcs = Rcw @ pw + tcw
    float pcx = R0*pwx + R1*pwy + R2*pwz + t0;
    float pcy = R3*pwx + R4*pwy + R5*pwz + t1;
    float pcz = R6*pwx + R7*pwy + R8*pwz + t2;

    float depth = pcz;
    float zs = (depth > 1e-6f) ? depth : 1e-6f;

    float ux = fx * pcx / zs + cxi;
    float uy = fy * pcy / zs + cyi;

    float alpha = 1.0f / (1.0f + expf(-alphas_raw[i]));

    float s0 = expf(scales_raw[3*i+0]);
    float s1 = expf(scales_raw[3*i+1]);
    float s2 = expf(scales_raw[3*i+2]);

    float qw = rots_raw[4*i+0], qx = rots_raw[4*i+1], qy = rots_raw[4*i+2], qz = rots_raw[4*i+3];
    float qn = sqrtf(qw*qw + qx*qx + qy*qy + qz*qz);
    qw /= qn; qx /= qn; qy /= qn; qz /= qn;

    float r00 = 1.0f - 2.0f*(qy*qy + qz*qz);
    float r01 = 2.0f*(qx*qy - qw*qz);
    float r02 = 2.0f*(qx*qz + qw*qy);
    float r10 = 2.0f*(qx*qy + qw*qz);
    float r11 = 1.0f - 2.0f*(qx*qx + qz*qz);
    float r12 = 2.0f*(qy*qz - qw*qx);
    float r20 = 2.0f*(qx*qz - qw*qy);
    float r21 = 2.0f*(qy*qz + qw*qx);
    float r22 = 1.0f - 2.0f*(qx*qx + qy*qy);

    // M = Rot * diag(scale)
    float m00 = r00*s0, m01 = r01*s1, m02 = r02*s2;
    float m10 = r10*s0, m11 = r11*s1, m12 = r12*s2;
    float m20 = r20*s0, m21 = r21*s1, m22 = r22*s2;

    // cov3d = M M^T (symmetric)
    float V00 = m00*m00 + m01*m01 + m02*m02;
    float V01 = m00*m10 + m01*m11 + m02*m12;
    float V02 = m00*m20 + m01*m21 + m02*m22;
    float V11 = m10*m10 + m11*m11 + m12*m12;
    float V12 = m10*m20 + m11*m21 + m12*m22;
    float V22 = m20*m20 + m21*m21 + m22*m22;

    float limx = 1.3f * ((float)IMG_W / (2.0f * fx));
    float limy = 1.3f * ((float)IMG_H / (2.0f * fy));
    float xzr = pcx / zs, yzr = pcy / zs;
    float txv = fminf(fmaxf(xzr, -limx), limx) * zs;
    float tyv = fminf(fmaxf(yzr, -limy), limy) * zs;

    float J00 = fx / zs, J02 = -fx * txv / (zs * zs);
    float J11 = fy / zs, J12 = -fy * tyv / (zs * zs);

    // T = J @ Rcw  (2x3)
    float T00 = J00*R0 + J02*R6, T01 = J00*R1 + J02*R7, T02 = J00*R2 + J02*R8;
    float T10 = J11*R3 + J12*R6, T11 = J11*R4 + J12*R7, T12 = J11*R5 + J12*R8;

    // TW = T @ cov3d
    float TW00 = T00*V00 + T01*V01 + T02*V02;
    float TW01 = T00*V01 + T01*V11 + T02*V12;
    float TW02 = T00*V02 + T01*V12 + T02*V22;
    float TW10 = T10*V00 + T11*V01 + T12*V02;
    float TW11 = T10*V01 + T11*V11 + T12*V12;
    float TW12 = T10*V02 + T11*V12 + T12*V22;

    // cov2d = TW @ T^T
    float c00 = TW00*T00 + TW01*T01 + TW02*T02;
    float c01 = TW00*T10 + TW01*T11 + TW02*T12;
    float c11 = TW10*T10 + TW11*T11 + TW12*T12;

    float a  = c00 + 0.3f;
    float b  = c01;
    float cc = c11 + 0.3f;
    float det = a * cc - b * b;
    float ci0 = cc / det;
    float ci1 = -b / det;
    float ci2 = a / det;

    float mid = 0.5f * (a + cc);
    float lam = mid + sqrtf(fmaxf(mid * mid - det, 0.1f));
    float radius = ceilf(3.0f * sqrtf(lam));
    areas_out[2*i + 0] = radius;
    areas_out[2*i + 1] = radius;

    // view dir: twc = -(Rcw^T @ tcw)
    float twcx = -(R0*t0 + R3*t1 + R6*t2);
    float twcy = -(R1*t0 + R4*t1 + R7*t2);
    float twcz = -(R2*t0 + R5*t1 + R8*t2);
    float dx = pwx - twcx, dy = pwy - twcy, dz = pwz - twcz;
    float dn = sqrtf(dx*dx + dy*dy + dz*dz);
    dx /= dn; dy /= dn; dz /= dn;

    float xx = dx*dx, yy = dy*dy, zz = dz*dz;
    float xy = dx*dy, yz = dy*dz, xz = dx*dz;

    // SH basis (16)
    float bas0  = SH_C0;
    float bas1  = -SH_C1 * dy;
    float bas2  =  SH_C1 * dz;
    float bas3  = -SH_C1 * dx;
    float bas4  = kC2[0] * xy;
    float bas5  = kC2[1] * yz;
    float bas6  = kC2[2] * (2.0f*zz - xx - yy);
    float bas7  = kC2[3] * xz;
    float bas8  = kC2[4] * (xx - yy);
    float bas9  = kC3[0] * dy * (3.0f*xx - yy);
    float bas10 = kC3[1] * xy * dz;
    float bas11 = kC3[2] * dy * (4.0f*zz - xx - yy);
    float bas12 = kC3[3] * dz * (2.0f*zz - 3.0f*xx - 3.0f*yy);
    float bas13 = kC3[4] * dx * (4.0f*zz - xx - yy);
    float bas14 = kC3[5] * dz * (xx - yy);
    float bas15 = kC3[6] * dx * (xx - 3.0f*yy);

    float col[3];
    #pragma unroll
    for (int c = 0; c < 3; ++c) {
        const float* hs = high_shs + 45*i + c;
        float acc = bas0 * low_shs[3*i + c];
        acc += bas1  * hs[0*3];
        acc += bas2  * hs[1*3];
        acc += bas3  * hs[2*3];
        acc += bas4  * hs[3*3];
        acc += bas5  * hs[4*3];
        acc += bas6  * hs[5*3];
        acc += bas7  * hs[6*3];
        acc += bas8  * hs[7*3];
        acc += bas9  * hs[8*3];
        acc += bas10 * hs[9*3];
        acc += bas11 * hs[10*3];
        acc += bas12 * hs[11*3];
        acc += bas13 * hs[12*3];
        acc += bas14 * hs[13*3];
        acc += bas15 * hs[14*3];
        col[c] = fmaxf(acc + 0.5f, 0.0f);
    }

    bool valid = depth > 0.2f;
    float al_eff = valid ? alpha : 0.0f;   // alpha=0 => ap=0 => exact same as reference's masking

    depth_ws[i] = depth;
    A_uns[i] = make_float4(ux, uy, ci0, ci1);
    B_uns[i] = make_float4(ci2, al_eff, col[0], col[1]);
    C_uns[i] = col[2];
}

// -------------------- Kernel 2: O(N^2) stable rank sort + gather --------------------
__global__ __launch_bounds__(256) void gs_ranksort(
    const float* __restrict__ depth,
    const float4* __restrict__ A_uns, const float4* __restrict__ B_uns,
    const float* __restrict__ C_uns,
    float4* __restrict__ A_s, float4* __restrict__ B_s, float* __restrict__ C_s)
{
    __shared__ float sd[GS_N];
    int tid = threadIdx.x;
    int gid = blockIdx.x * 256 + tid;
    for (int j = tid; j < GS_N; j += 256) sd[j] = depth[j];
    __syncthreads();

    float mg = sd[gid];
    int rank = 0;
    const float4* s4 = (const float4*)sd;
    #pragma unroll 8
    for (int jj = 0; jj < GS_N/4; ++jj) {
        float4 v = s4[jj];
        int j0 = jj * 4;
        rank += (v.x < mg || (v.x == mg && (j0+0) < gid)) ? 1 : 0;
        rank += (v.y < mg || (v.y == mg && (j0+1) < gid)) ? 1 : 0;
        rank += (v.z < mg || (v.z == mg && (j0+2) < gid)) ? 1 : 0;
        rank += (v.w < mg || (v.w == mg && (j0+3) < gid)) ? 1 : 0;
    }
    A_s[rank] = A_uns[gid];
    B_s[rank] = B_uns[gid];
    C_s[rank] = C_uns[gid];
}

// -------------------- Kernel 3: wave-per-pixel alpha compositing --------------------
// One wave (64 lanes) per pixel. Lane l evaluates gaussian chunk*64+l; a
// 6-step shfl_up prefix product of (1-ap) reconstructs each lane's exact
// transmittance tau. carry (wave-uniform) composes chunks. Early exit when
// carry <= 1e-4 is exact: every factor (1-ap) <= 1 so tau <= carry forever.
__global__ __launch_bounds__(256) void gs_raster(
    const float4* __restrict__ A_s, const float4* __restrict__ B_s,
    const float* __restrict__ C_s, float* __restrict__ img)
{
    int lane = threadIdx.x & 63;
    int wv   = threadIdx.x >> 6;
    int p    = blockIdx.x * 4 + wv;          // 2304 blocks x 4 waves
    float px = (float)(p % IMG_W);
    float py = (float)(p / IMG_W);

    float carry = 1.0f;
    float accr = 0.0f, accg = 0.0f, accb = 0.0f;

    for (int c = 0; c < GS_N / 64; ++c) {
        int n = c * 64 + lane;
        float4 a4 = A_s[n];      // coalesced float4 across the wave
        float4 b4 = B_s[n];
        float  cb = C_s[n];

        float ddx = a4.x - px;
        float ddy = a4.y - py;
        float pw = -0.5f * (a4.z * ddx * ddx + b4.x * ddy * ddy) - a4.w * ddx * ddy;
        pw = fminf(pw, 0.0f);
        float ap = b4.y * __expf(pw);
        ap = fminf(ap, 0.99f);
        ap = (ap >= (1.0f / 255.0f)) ? ap : 0.0f;

        float f = 1.0f - ap;
        // inclusive prefix product across 64 lanes (Hillis-Steele)
        float incl = f;
        #pragma unroll
        for (int d = 1; d < 64; d <<= 1) {
            float v = __shfl_up(incl, d, 64);
            if (lane >= d) incl *= v;
        }
        float excl = __shfl_up(incl, 1, 64);
        if (lane == 0) excl = 1.0f;

        float tau = carry * excl;
        float wgt = (tau > 1e-4f) ? ap * tau : 0.0f;
        accr += b4.z * wgt;
        accg += b4.w * wgt;
        accb += cb  * wgt;

        carry *= __shfl(incl, 63, 64);       // wave-uniform chunk transmittance
        if (carry <= 1e-4f) break;           // wave-uniform exact early exit
    }

    // wave reduction of the three accumulators
    #pragma unroll
    for (int d = 32; d >= 1; d >>= 1) {
        accr += __shfl_xor(accr, d, 64);
        accg += __shfl_xor(accg, d, 64);
        accb += __shfl_xor(accb, d, 64);
    }
    if (lane == 0) {
        img[0 * NPIX + p] = accr;
        img[1 * NPIX + p] = accg;
        img[2 * NPIX + p] = accb;
    }
}

extern "C" void kernel_launch(void* const* d_in, const int* in_sizes, int n_in,
                              void* d_out, int out_size, void* d_ws, size_t ws_size,
                              hipStream_t stream) {
    const float* pws        = (const float*)d_in[0];
    const float* low_shs    = (const float*)d_in[1];
    const float* high_shs   = (const float*)d_in[2];
    const float* alphas_raw = (const float*)d_in[3];
    const float* scales_raw = (const float*)d_in[4];
    const float* rots_raw   = (const float*)d_in[5];
    // d_in[6] = us (unused by the forward pass)
    const float* Rcw        = (const float*)d_in[7];
    const float* tcw        = (const float*)d_in[8];
    const float* cam        = (const float*)d_in[9];

    float* out_img   = (float*)d_out;             // 3*96*96
    float* out_areas = (float*)d_out + 3 * NPIX;  // N*2

    // workspace layout (bytes)
    char* ws = (char*)d_ws;
    float*  depth_ws = (float*)(ws + 0);                    // N floats   (16 KB)
    float4* A_uns    = (float4*)(ws + 16384);               // N float4   (64 KB)
    float4* B_uns    = (float4*)(ws + 16384 + 65536);       // N float4
    float*  C_uns    = (float*)(ws + 16384 + 2*65536);      // N floats
    float4* A_s      = (float4*)(ws + 2*16384 + 2*65536);   // N float4
    float4* B_s      = (float4*)(ws + 2*16384 + 3*65536);   // N float4
    float*  C_s      = (float*)(ws + 2*16384 + 4*65536);    // N floats

    gs_prep<<<GS_N / 256, 256, 0, stream>>>(
        pws, low_shs, high_shs, alphas_raw, scales_raw, rots_raw, Rcw, tcw, cam,
        out_areas, depth_ws, A_uns, B_uns, C_uns);

    gs_ranksort<<<GS_N / 256, 256, 0, stream>>>(
        depth_ws, A_uns, B_uns, C_uns, A_s, B_s, C_s);

    gs_raster<<<NPIX / 256 / 4 * 4 + ((NPIX % (4*64)) ? 1 : 0), 256, 0, stream>>>(A_s, B_s, C_s, out_img);
    // NPIX = 9216 = 2304 * 4 exactly; grid computes to 2304.
}

// Round 3
// 119.878 us; speedup vs baseline: 9.2798x; 1.9149x over previous
//
#include <hip/hip_runtime.h>
#include <hip/hip_bf16.h>
#include <math.h>

#define GS_N 4096
#define IMG_H 96
#define IMG_W 96
#define NPIX (IMG_H * IMG_W)

// SH constants
#define SH_C0 0.28209479177387814f
#define SH_C1 0.4886025119029199f
__device__ __constant__ float kC2[5] = {1.0925484305920792f, -1.0925484305920792f, 0.31539156525252005f, -1.0925484305920792f, 0.5462742152960396f};
__device__ __constant__ float kC3[7] = {-0.5900435899266435f, 2.890611442640554f, -0.4570457994644658f, 0.3731763325901154f, -0.4570457994644658f, 1.445305721320277f, -0.5900435899266435f};

// -------------------- Kernel 1: per-gaussian preprocessing --------------------
__global__ __launch_bounds__(256) void gs_prep(
    const float* __restrict__ pws, const float* __restrict__ low_shs,
    const float* __restrict__ high_shs, const float* __restrict__ alphas_raw,
    const float* __restrict__ scales_raw, const float* __restrict__ rots_raw,
    const float* __restrict__ Rcw, const float* __restrict__ tcw,
    const float* __restrict__ cam,
    float* __restrict__ areas_out,      // N*2, original order (part of d_out)
    float* __restrict__ depth_ws,       // N
    int*   __restrict__ rank_ws,        // N (zeroed here for the atomic partial-rank)
    float4* __restrict__ A_uns,         // {ux, uy, ci0, ci1}
    float4* __restrict__ B_uns,         // {ci2, alpha_eff, colR, colG}
    float* __restrict__ C_uns)          // colB
{
    int i = blockIdx.x * 256 + threadIdx.x;
    if (i >= GS_N) return;

    rank_ws[i] = 0;   // ws is poisoned 0xAA before every launch; zero it here

    float fx = cam[0], fy = cam[1], cxi = cam[2], cyi = cam[3];
    float R0 = Rcw[0], R1 = Rcw[1], R2 = Rcw[2];
    float R3 = Rcw[3], R4 = Rcw[4], R5 = Rcw[5];
    float R6 = Rcw[6], R7 = Rcw[7], R8 = Rcw[8];
    float t0 = tcw[0], t1 = tcw[1], t2 = tcw[2];

    float pwx = pws[3*i+0], pwy = pws[3*i+1], pwz = pws[3*i+2];

    // camera-space point: pcs = Rcw @ pw + tcw
    float pcx = R0*pwx + R1*pwy + R2*pwz + t0;
    float pcy = R3*pwx + R4*pwy + R5*pwz + t1;
    float pcz = R6*pwx + R7*pwy + R8*pwz + t2;

    float depth = pcz;
    float zs = (depth > 1e-6f) ? depth : 1e-6f;

    float ux = fx * pcx / zs + cxi;
    float uy = fy * pcy / zs + cyi;

    float alpha = 1.0f / (1.0f + expf(-alphas_raw[i]));

    float s0 = expf(scales_raw[3*i+0]);
    float s1 = expf(scales_raw[3*i+1]);
    float s2 = expf(scales_raw[3*i+2]);

    float qw = rots_raw[4*i+0], qx = rots_raw[4*i+1], qy = rots_raw[4*i+2], qz = rots_raw[4*i+3];
    float qn = sqrtf(qw*qw + qx*qx + qy*qy + qz*qz);
    qw /= qn; qx /= qn; qy /= qn; qz /= qn;

    float r00 = 1.0f - 2.0f*(qy*qy + qz*qz);
    float r01 = 2.0f*(qx*qy - qw*qz);
    float r02 = 2.0f*(qx*qz + qw*qy);
    float r10 = 2.0f*(qx*qy + qw*qz);
    float r11 = 1.0f - 2.0f*(qx*qx + qz*qz);
    float r12 = 2.0f*(qy*qz - qw*qx);
    float r20 = 2.0f*(qx*qz - qw*qy);
    float r21 = 2.0f*(qy*qz + qw*qx);
    float r22 = 1.0f - 2.0f*(qx*qx + qy*qy);

    // M = Rot * diag(scale)
    float m00 = r00*s0, m01 = r01*s1, m02 = r02*s2;
    float m10 = r10*s0, m11 = r11*s1, m12 = r12*s2;
    float m20 = r20*s0, m21 = r21*s1, m22 = r22*s2;

    // cov3d = M M^T (symmetric)
    float V00 = m00*m00 + m01*m01 + m02*m02;
    float V01 = m00*m10 + m01*m11 + m02*m12;
    float V02 = m00*m20 + m01*m21 + m02*m22;
    float V11 = m10*m10 + m11*m11 + m12*m12;
    float V12 = m10*m20 + m11*m21 + m12*m22;
    float V22 = m20*m20 + m21*m21 + m22*m22;

    float limx = 1.3f * ((float)IMG_W / (2.0f * fx));
    float limy = 1.3f * ((float)IMG_H / (2.0f * fy));
    float xzr = pcx / zs, yzr = pcy / zs;
    float txv = fminf(fmaxf(xzr, -limx), limx) * zs;
    float tyv = fminf(fmaxf(yzr, -limy), limy) * zs;

    float J00 = fx / zs, J02 = -fx * txv / (zs * zs);
    float J11 = fy / zs, J12 = -fy * tyv / (zs * zs);

    // T = J @ Rcw  (2x3)
    float T00 = J00*R0 + J02*R6, T01 = J00*R1 + J02*R7, T02 = J00*R2 + J02*R8;
    float T10 = J11*R3 + J12*R6, T11 = J11*R4 + J12*R7, T12 = J11*R5 + J12*R8;

    // TW = T @ cov3d
    float TW00 = T00*V00 + T01*V01 + T02*V02;
    float TW01 = T00*V01 + T01*V11 + T02*V12;
    float TW02 = T00*V02 + T01*V12 + T02*V22;
    float TW10 = T10*V00 + T11*V01 + T12*V02;
    float TW11 = T10*V01 + T11*V11 + T12*V12;
    float TW12 = T10*V02 + T11*V12 + T12*V22;

    // cov2d = TW @ T^T
    float c00 = TW00*T00 + TW01*T01 + TW02*T02;
    float c01 = TW00*T10 + TW01*T11 + TW02*T12;
    float c11 = TW10*T10 + TW11*T11 + TW12*T12;

    float a  = c00 + 0.3f;
    float b  = c01;
    float cc = c11 + 0.3f;
    float det = a * cc - b * b;
    float ci0 = cc / det;
    float ci1 = -b / det;
    float ci2 = a / det;

    float mid = 0.5f * (a + cc);
    float lam = mid + sqrtf(fmaxf(mid * mid - det, 0.1f));
    float radius = ceilf(3.0f * sqrtf(lam));
    areas_out[2*i + 0] = radius;
    areas_out[2*i + 1] = radius;

    // view dir: twc = -(Rcw^T @ tcw)
    float twcx = -(R0*t0 + R3*t1 + R6*t2);
    float twcy = -(R1*t0 + R4*t1 + R7*t2);
    float twcz = -(R2*t0 + R5*t1 + R8*t2);
    float dx = pwx - twcx, dy = pwy - twcy, dz = pwz - twcz;
    float dn = sqrtf(dx*dx + dy*dy + dz*dz);
    dx /= dn; dy /= dn; dz /= dn;

    float xx = dx*dx, yy = dy*dy, zz = dz*dz;
    float xy = dx*dy, yz = dy*dz, xz = dx*dz;

    // SH basis (16)
    float bas0  = SH_C0;
    float bas1  = -SH_C1 * dy;
    float bas2  =  SH_C1 * dz;
    float bas3  = -SH_C1 * dx;
    float bas4  = kC2[0] * xy;
    float bas5  = kC2[1] * yz;
    float bas6  = kC2[2] * (2.0f*zz - xx - yy);
    float bas7  = kC2[3] * xz;
    float bas8  = kC2[4] * (xx - yy);
    float bas9  = kC3[0] * dy * (3.0f*xx - yy);
    float bas10 = kC3[1] * xy * dz;
    float bas11 = kC3[2] * dy * (4.0f*zz - xx - yy);
    float bas12 = kC3[3] * dz * (2.0f*zz - 3.0f*xx - 3.0f*yy);
    float bas13 = kC3[4] * dx * (4.0f*zz - xx - yy);
    float bas14 = kC3[5] * dz * (xx - yy);
    float bas15 = kC3[6] * dx * (xx - 3.0f*yy);

    float col[3];
    #pragma unroll
    for (int c = 0; c < 3; ++c) {
        const float* hs = high_shs + 45*i + c;
        float acc = bas0 * low_shs[3*i + c];
        acc += bas1  * hs[0*3];
        acc += bas2  * hs[1*3];
        acc += bas3  * hs[2*3];
        acc += bas4  * hs[3*3];
        acc += bas5  * hs[4*3];
        acc += bas6  * hs[5*3];
        acc += bas7  * hs[6*3];
        acc += bas8  * hs[7*3];
        acc += bas9  * hs[8*3];
        acc += bas10 * hs[9*3];
        acc += bas11 * hs[10*3];
        acc += bas12 * hs[11*3];
        acc += bas13 * hs[12*3];
        acc += bas14 * hs[13*3];
        acc += bas15 * hs[14*3];
        col[c] = fmaxf(acc + 0.5f, 0.0f);
    }

    bool valid = depth > 0.2f;
    float al_eff = valid ? alpha : 0.0f;   // alpha=0 => ap=0 => same as reference masking

    depth_ws[i] = depth;
    A_uns[i] = make_float4(ux, uy, ci0, ci1);
    B_uns[i] = make_float4(ci2, al_eff, col[0], col[1]);
    C_uns[i] = col[2];
}

// -------------------- Kernel 2a: tiled partial rank (16x16 tile grid) --------------------
// rank[i] = #{ j : depth[j] < depth[i]  or (depth[j]==depth[i] and j<i) }  (stable argsort)
// Block (itile,jtile): 256 i's vs a 256-j chunk staged in LDS; atomicAdd partials.
__global__ __launch_bounds__(256) void gs_rank_partial(
    const float* __restrict__ depth, int* __restrict__ rank_ws)
{
    __shared__ float sd[256];
    int itile = blockIdx.x >> 4;
    int jtile = blockIdx.x & 15;
    int tid = threadIdx.x;
    int i = itile * 256 + tid;

    sd[tid] = depth[jtile * 256 + tid];
    __syncthreads();

    float mg = depth[i];
    int jbase = jtile * 256;
    int rank = 0;
    const float4* s4 = (const float4*)sd;   // broadcast reads: all lanes same addr
    #pragma unroll 16
    for (int jj = 0; jj < 64; ++jj) {
        float4 v = s4[jj];
        int j0 = jbase + jj * 4;
        rank += (v.x < mg || (v.x == mg && (j0+0) < i)) ? 1 : 0;
        rank += (v.y < mg || (v.y == mg && (j0+1) < i)) ? 1 : 0;
        rank += (v.z < mg || (v.z == mg && (j0+2) < i)) ? 1 : 0;
        rank += (v.w < mg || (v.w == mg && (j0+3) < i)) ? 1 : 0;
    }
    atomicAdd(&rank_ws[i], rank);
}

// -------------------- Kernel 2b: gather into sorted SoA --------------------
__global__ __launch_bounds__(256) void gs_gather(
    const int* __restrict__ rank_ws,
    const float4* __restrict__ A_uns, const float4* __restrict__ B_uns,
    const float* __restrict__ C_uns,
    float4* __restrict__ A_s, float4* __restrict__ B_s, float* __restrict__ C_s)
{
    int i = blockIdx.x * 256 + threadIdx.x;
    int r = rank_ws[i];
    A_s[r] = A_uns[i];
    B_s[r] = B_uns[i];
    C_s[r] = C_uns[i];
}

// -------------------- Kernel 3: wave-per-pixel alpha compositing --------------------
// One wave (64 lanes) per pixel. Lane l evaluates gaussian chunk*64+l; a
// 6-step shfl_up prefix product of (1-ap) reconstructs each lane's exact
// transmittance tau. carry (wave-uniform) composes chunks. Early exit when
// carry <= 1e-4 is exact: every factor (1-ap) <= 1 so tau <= carry forever.
__global__ __launch_bounds__(256) void gs_raster(
    const float4* __restrict__ A_s, const float4* __restrict__ B_s,
    const float* __restrict__ C_s, float* __restrict__ img)
{
    int lane = threadIdx.x & 63;
    int wv   = threadIdx.x >> 6;
    int p    = blockIdx.x * 4 + wv;          // 2304 blocks x 4 waves
    float px = (float)(p % IMG_W);
    float py = (float)(p / IMG_W);

    float carry = 1.0f;
    float accr = 0.0f, accg = 0.0f, accb = 0.0f;

    for (int c = 0; c < GS_N / 64; ++c) {
        int n = c * 64 + lane;
        float4 a4 = A_s[n];      // coalesced float4 across the wave
        float4 b4 = B_s[n];
        float  cb = C_s[n];

        float ddx = a4.x - px;
        float ddy = a4.y - py;
        float pw = -0.5f * (a4.z * ddx * ddx + b4.x * ddy * ddy) - a4.w * ddx * ddy;
        pw = fminf(pw, 0.0f);
        float ap = b4.y * __expf(pw);
        ap = fminf(ap, 0.99f);
        ap = (ap >= (1.0f / 255.0f)) ? ap : 0.0f;

        float f = 1.0f - ap;
        // inclusive prefix product across 64 lanes (Hillis-Steele)
        float incl = f;
        #pragma unroll
        for (int d = 1; d < 64; d <<= 1) {
            float v = __shfl_up(incl, d, 64);
            if (lane >= d) incl *= v;
        }
        float excl = __shfl_up(incl, 1, 64);
        if (lane == 0) excl = 1.0f;

        float tau = carry * excl;
        float wgt = (tau > 1e-4f) ? ap * tau : 0.0f;
        accr += b4.z * wgt;
        accg += b4.w * wgt;
        accb += cb  * wgt;

        carry *= __shfl(incl, 63, 64);       // wave-uniform chunk transmittance
        if (carry <= 1e-4f) break;           // wave-uniform exact early exit
    }

    // wave reduction of the three accumulators
    #pragma unroll
    for (int d = 32; d >= 1; d >>= 1) {
        accr += __shfl_xor(accr, d, 64);
        accg += __shfl_xor(accg, d, 64);
        accb += __shfl_xor(accb, d, 64);
    }
    if (lane == 0) {
        img[0 * NPIX + p] = accr;
        img[1 * NPIX + p] = accg;
        img[2 * NPIX + p] = accb;
    }
}

extern "C" void kernel_launch(void* const* d_in, const int* in_sizes, int n_in,
                              void* d_out, int out_size, void* d_ws, size_t ws_size,
                              hipStream_t stream) {
    const float* pws        = (const float*)d_in[0];
    const float* low_shs    = (const float*)d_in[1];
    const float* high_shs   = (const float*)d_in[2];
    const float* alphas_raw = (const float*)d_in[3];
    const float* scales_raw = (const float*)d_in[4];
    const float* rots_raw   = (const float*)d_in[5];
    // d_in[6] = us (unused by the forward pass)
    const float* Rcw        = (const float*)d_in[7];
    const float* tcw        = (const float*)d_in[8];
    const float* cam        = (const float*)d_in[9];

    float* out_img   = (float*)d_out;             // 3*96*96
    float* out_areas = (float*)d_out + 3 * NPIX;  // N*2

    // workspace layout (bytes)
    char* ws = (char*)d_ws;
    float*  depth_ws = (float*)(ws + 0);            // 16 KB
    int*    rank_ws  = (int*)  (ws + 16384);        // 16 KB
    float4* A_uns    = (float4*)(ws + 32768);       // 64 KB
    float4* B_uns    = (float4*)(ws + 98304);       // 64 KB
    float*  C_uns    = (float*)(ws + 163840);       // 16 KB
    float4* A_s      = (float4*)(ws + 180224);      // 64 KB
    float4* B_s      = (float4*)(ws + 245760);      // 64 KB
    float*  C_s      = (float*)(ws + 311296);       // 16 KB

    gs_prep<<<GS_N / 256, 256, 0, stream>>>(
        pws, low_shs, high_shs, alphas_raw, scales_raw, rots_raw, Rcw, tcw, cam,
        out_areas, depth_ws, rank_ws, A_uns, B_uns, C_uns);

    gs_rank_partial<<<256, 256, 0, stream>>>(depth_ws, rank_ws);

    gs_gather<<<GS_N / 256, 256, 0, stream>>>(
        rank_ws, A_uns, B_uns, C_uns, A_s, B_s, C_s);

    gs_raster<<<NPIX / (4 * 64), 256, 0, stream>>>(A_s, B_s, C_s, out_img);
}

// Round 4
// 102.696 us; speedup vs baseline: 10.8324x; 1.1673x over previous
//
#include <hip/hip_runtime.h>
#include <hip/hip_bf16.h>
#include <math.h>

#define GS_N 4096
#define IMG_H 96
#define IMG_W 96
#define NPIX (IMG_H * IMG_W)
#define TILE_PX 12
#define TILES_X 8
#define NTILES (TILES_X * TILES_X)          // 64 tiles of 12x12 px
#define WAVES_PER_TILE 36                    // 144 px / 4 waves-per-block

// SH constants
#define SH_C0 0.28209479177387814f
#define SH_C1 0.4886025119029199f
__device__ __constant__ float kC2[5] = {1.0925484305920792f, -1.0925484305920792f, 0.31539156525252005f, -1.0925484305920792f, 0.5462742152960396f};
__device__ __constant__ float kC3[7] = {-0.5900435899266435f, 2.890611442640554f, -0.4570457994644658f, 0.3731763325901154f, -0.4570457994644658f, 1.445305721320277f, -0.5900435899266435f};

// -------------------- Kernel 1: per-gaussian preprocessing --------------------
__global__ __launch_bounds__(256) void gs_prep(
    const float* __restrict__ pws, const float* __restrict__ low_shs,
    const float* __restrict__ high_shs, const float* __restrict__ alphas_raw,
    const float* __restrict__ scales_raw, const float* __restrict__ rots_raw,
    const float* __restrict__ Rcw, const float* __restrict__ tcw,
    const float* __restrict__ cam,
    float* __restrict__ areas_out,      // N*2, original order (part of d_out)
    float* __restrict__ depth_ws,       // N
    int*   __restrict__ rank_ws,        // N (zeroed here for the atomic partial-rank)
    float4* __restrict__ A_uns,         // {ux, uy, ci0, ci1}
    float4* __restrict__ B_uns,         // {ci2, alpha_eff, colR, colG}
    float* __restrict__ C_uns,          // colB
    float4* __restrict__ D_uns)         // {ux, uy, rx, ry} bbox (rx<0 => culled)
{
    int i = blockIdx.x * 256 + threadIdx.x;
    if (i >= GS_N) return;

    rank_ws[i] = 0;   // ws is poisoned 0xAA before every launch; zero it here

    float fx = cam[0], fy = cam[1], cxi = cam[2], cyi = cam[3];
    float R0 = Rcw[0], R1 = Rcw[1], R2 = Rcw[2];
    float R3 = Rcw[3], R4 = Rcw[4], R5 = Rcw[5];
    float R6 = Rcw[6], R7 = Rcw[7], R8 = Rcw[8];
    float t0 = tcw[0], t1 = tcw[1], t2 = tcw[2];

    float pwx = pws[3*i+0], pwy = pws[3*i+1], pwz = pws[3*i+2];

    // camera-space point: pcs = Rcw @ pw + tcw
    float pcx = R0*pwx + R1*pwy + R2*pwz + t0;
    float pcy = R3*pwx + R4*pwy + R5*pwz + t1;
    float pcz = R6*pwx + R7*pwy + R8*pwz + t2;

    float depth = pcz;
    float zs = (depth > 1e-6f) ? depth : 1e-6f;

    float ux = fx * pcx / zs + cxi;
    float uy = fy * pcy / zs + cyi;

    float alpha = 1.0f / (1.0f + expf(-alphas_raw[i]));

    float s0 = expf(scales_raw[3*i+0]);
    float s1 = expf(scales_raw[3*i+1]);
    float s2 = expf(scales_raw[3*i+2]);

    float qw = rots_raw[4*i+0], qx = rots_raw[4*i+1], qy = rots_raw[4*i+2], qz = rots_raw[4*i+3];
    float qn = sqrtf(qw*qw + qx*qx + qy*qy + qz*qz);
    qw /= qn; qx /= qn; qy /= qn; qz /= qn;

    float r00 = 1.0f - 2.0f*(qy*qy + qz*qz);
    float r01 = 2.0f*(qx*qy - qw*qz);
    float r02 = 2.0f*(qx*qz + qw*qy);
    float r10 = 2.0f*(qx*qy + qw*qz);
    float r11 = 1.0f - 2.0f*(qx*qx + qz*qz);
    float r12 = 2.0f*(qy*qz - qw*qx);
    float r20 = 2.0f*(qx*qz - qw*qy);
    float r21 = 2.0f*(qy*qz + qw*qx);
    float r22 = 1.0f - 2.0f*(qx*qx + qy*qy);

    // M = Rot * diag(scale)
    float m00 = r00*s0, m01 = r01*s1, m02 = r02*s2;
    float m10 = r10*s0, m11 = r11*s1, m12 = r12*s2;
    float m20 = r20*s0, m21 = r21*s1, m22 = r22*s2;

    // cov3d = M M^T (symmetric)
    float V00 = m00*m00 + m01*m01 + m02*m02;
    float V01 = m00*m10 + m01*m11 + m02*m12;
    float V02 = m00*m20 + m01*m21 + m02*m22;
    float V11 = m10*m10 + m11*m11 + m12*m12;
    float V12 = m10*m20 + m11*m21 + m12*m22;
    float V22 = m20*m20 + m21*m21 + m22*m22;

    float limx = 1.3f * ((float)IMG_W / (2.0f * fx));
    float limy = 1.3f * ((float)IMG_H / (2.0f * fy));
    float xzr = pcx / zs, yzr = pcy / zs;
    float txv = fminf(fmaxf(xzr, -limx), limx) * zs;
    float tyv = fminf(fmaxf(yzr, -limy), limy) * zs;

    float J00 = fx / zs, J02 = -fx * txv / (zs * zs);
    float J11 = fy / zs, J12 = -fy * tyv / (zs * zs);

    // T = J @ Rcw  (2x3)
    float T00 = J00*R0 + J02*R6, T01 = J00*R1 + J02*R7, T02 = J00*R2 + J02*R8;
    float T10 = J11*R3 + J12*R6, T11 = J11*R4 + J12*R7, T12 = J11*R5 + J12*R8;

    // TW = T @ cov3d
    float TW00 = T00*V00 + T01*V01 + T02*V02;
    float TW01 = T00*V01 + T01*V11 + T02*V12;
    float TW02 = T00*V02 + T01*V12 + T02*V22;
    float TW10 = T10*V00 + T11*V01 + T12*V02;
    float TW11 = T10*V01 + T11*V11 + T12*V12;
    float TW12 = T10*V02 + T11*V12 + T12*V22;

    // cov2d = TW @ T^T
    float c00 = TW00*T00 + TW01*T01 + TW02*T02;
    float c01 = TW00*T10 + TW01*T11 + TW02*T12;
    float c11 = TW10*T10 + TW11*T11 + TW12*T12;

    float a  = c00 + 0.3f;
    float b  = c01;
    float cc = c11 + 0.3f;
    float det = a * cc - b * b;
    float ci0 = cc / det;
    float ci1 = -b / det;
    float ci2 = a / det;

    float mid = 0.5f * (a + cc);
    float lam = mid + sqrtf(fmaxf(mid * mid - det, 0.1f));
    float radius = ceilf(3.0f * sqrtf(lam));
    areas_out[2*i + 0] = radius;
    areas_out[2*i + 1] = radius;

    // view dir: twc = -(Rcw^T @ tcw)
    float twcx = -(R0*t0 + R3*t1 + R6*t2);
    float twcy = -(R1*t0 + R4*t1 + R7*t2);
    float twcz = -(R2*t0 + R5*t1 + R8*t2);
    float dx = pwx - twcx, dy = pwy - twcy, dz = pwz - twcz;
    float dn = sqrtf(dx*dx + dy*dy + dz*dz);
    dx /= dn; dy /= dn; dz /= dn;

    float xx = dx*dx, yy = dy*dy, zz = dz*dz;
    float xy = dx*dy, yz = dy*dz, xz = dx*dz;

    // SH basis (16)
    float bas0  = SH_C0;
    float bas1  = -SH_C1 * dy;
    float bas2  =  SH_C1 * dz;
    float bas3  = -SH_C1 * dx;
    float bas4  = kC2[0] * xy;
    float bas5  = kC2[1] * yz;
    float bas6  = kC2[2] * (2.0f*zz - xx - yy);
    float bas7  = kC2[3] * xz;
    float bas8  = kC2[4] * (xx - yy);
    float bas9  = kC3[0] * dy * (3.0f*xx - yy);
    float bas10 = kC3[1] * xy * dz;
    float bas11 = kC3[2] * dy * (4.0f*zz - xx - yy);
    float bas12 = kC3[3] * dz * (2.0f*zz - 3.0f*xx - 3.0f*yy);
    float bas13 = kC3[4] * dx * (4.0f*zz - xx - yy);
    float bas14 = kC3[5] * dz * (xx - yy);
    float bas15 = kC3[6] * dx * (xx - 3.0f*yy);

    float col[3];
    #pragma unroll
    for (int c = 0; c < 3; ++c) {
        const float* hs = high_shs + 45*i + c;
        float acc = bas0 * low_shs[3*i + c];
        acc += bas1  * hs[0*3];
        acc += bas2  * hs[1*3];
        acc += bas3  * hs[2*3];
        acc += bas4  * hs[3*3];
        acc += bas5  * hs[4*3];
        acc += bas6  * hs[5*3];
        acc += bas7  * hs[6*3];
        acc += bas8  * hs[7*3];
        acc += bas9  * hs[8*3];
        acc += bas10 * hs[9*3];
        acc += bas11 * hs[10*3];
        acc += bas12 * hs[11*3];
        acc += bas13 * hs[12*3];
        acc += bas14 * hs[13*3];
        acc += bas15 * hs[14*3];
        col[c] = fmaxf(acc + 0.5f, 0.0f);
    }

    bool valid = depth > 0.2f;
    float al_eff = valid ? alpha : 0.0f;   // alpha=0 => ap=0 => same as reference masking

    // Visibility ellipse: ap>=1/255 <=> Q <= T, T = ln(255*alpha).
    // Max extent of {Q<=T} along x is sqrt(2*T*Cxx) (C = dilated covariance).
    // +1e-4 margin makes the cull strictly conservative vs float rounding.
    float Tthr = __logf(255.0f * al_eff) + 1e-4f;
    float rx = (Tthr > 0.0f) ? sqrtf(2.0f * Tthr * a)  : -1.0f;
    float ry = (Tthr > 0.0f) ? sqrtf(2.0f * Tthr * cc) : -1.0f;

    depth_ws[i] = depth;
    A_uns[i] = make_float4(ux, uy, ci0, ci1);
    B_uns[i] = make_float4(ci2, al_eff, col[0], col[1]);
    C_uns[i] = col[2];
    D_uns[i] = make_float4(ux, uy, rx, ry);
}

// -------------------- Kernel 2a: tiled partial rank (16x16 tile grid) --------------------
// rank[i] = #{ j : depth[j] < depth[i]  or (depth[j]==depth[i] and j<i) }  (stable argsort)
__global__ __launch_bounds__(256) void gs_rank_partial(
    const float* __restrict__ depth, int* __restrict__ rank_ws)
{
    __shared__ float sd[256];
    int itile = blockIdx.x >> 4;
    int jtile = blockIdx.x & 15;
    int tid = threadIdx.x;
    int i = itile * 256 + tid;

    sd[tid] = depth[jtile * 256 + tid];
    __syncthreads();

    float mg = depth[i];
    int jbase = jtile * 256;
    int rank = 0;
    const float4* s4 = (const float4*)sd;   // broadcast reads: all lanes same addr
    #pragma unroll 16
    for (int jj = 0; jj < 64; ++jj) {
        float4 v = s4[jj];
        int j0 = jbase + jj * 4;
        rank += (v.x < mg || (v.x == mg && (j0+0) < i)) ? 1 : 0;
        rank += (v.y < mg || (v.y == mg && (j0+1) < i)) ? 1 : 0;
        rank += (v.z < mg || (v.z == mg && (j0+2) < i)) ? 1 : 0;
        rank += (v.w < mg || (v.w == mg && (j0+3) < i)) ? 1 : 0;
    }
    atomicAdd(&rank_ws[i], rank);
}

// -------------------- Kernel 2b: gather into sorted SoA --------------------
__global__ __launch_bounds__(256) void gs_gather(
    const int* __restrict__ rank_ws,
    const float4* __restrict__ A_uns, const float4* __restrict__ B_uns,
    const float* __restrict__ C_uns, const float4* __restrict__ D_uns,
    float4* __restrict__ A_s, float4* __restrict__ B_s, float* __restrict__ C_s,
    float4* __restrict__ D_s)
{
    int i = blockIdx.x * 256 + threadIdx.x;
    int r = rank_ws[i];
    A_s[r] = A_uns[i];
    B_s[r] = B_uns[i];
    C_s[r] = C_uns[i];
    D_s[r] = D_uns[i];
}

// -------------------- Kernel 2c: per-tile binning (order-preserving compaction) ------
// One block per 12x12 tile. Walks sorted gaussians; ballot-compacts indices of
// those whose conservative bbox intersects the tile into tile_list (depth order).
__global__ __launch_bounds__(256) void gs_bin(
    const float4* __restrict__ D_s,
    int* __restrict__ tile_list, int* __restrict__ tile_cnt)
{
    __shared__ int s_base;
    __shared__ int warp_off[4];
    int tile = blockIdx.x;
    int tx = tile & (TILES_X - 1), ty = tile >> 3;
    float x0 = (float)(tx * TILE_PX), x1 = (float)(tx * TILE_PX + TILE_PX - 1);
    float y0 = (float)(ty * TILE_PX), y1 = (float)(ty * TILE_PX + TILE_PX - 1);

    int tid = threadIdx.x;
    int lane = tid & 63, w = tid >> 6;
    if (tid == 0) s_base = 0;
    __syncthreads();

    int* list = tile_list + tile * GS_N;

    for (int r = 0; r < GS_N / 256; ++r) {
        int g = r * 256 + tid;
        float4 d = D_s[g];
        bool pred = (d.z >= 0.0f) &&
                    (d.x - d.z <= x1) && (d.x + d.z >= x0) &&
                    (d.y - d.w <= y1) && (d.y + d.w >= y0);
        unsigned long long m = __ballot(pred);
        int before = __popcll(m & ((1ull << lane) - 1ull));
        int wcnt = __popcll(m);
        if (lane == 0) warp_off[w] = wcnt;
        __syncthreads();
        int off = s_base;
        #pragma unroll
        for (int k = 0; k < 4; ++k) if (k < w) off += warp_off[k];
        if (pred) list[off + before] = g;
        __syncthreads();
        if (tid == 0) s_base += warp_off[0] + warp_off[1] + warp_off[2] + warp_off[3];
        // s_base update is ordered before next iteration's read by the next
        // iteration's first __syncthreads.
    }
    __syncthreads();
    if (tid == 0) tile_cnt[tile] = s_base;
}

// -------------------- Kernel 3: wave-per-pixel compositing over tile list -----------
// Block = 4 waves = 4 pixels of one tile; 36 blocks per tile. Lane l evaluates
// list entry chunk*64+l; shfl_up prefix product of (1-ap) gives exact per-entry
// transmittance. Entries outside the list contribute f=1 (identity).
__global__ __launch_bounds__(256) void gs_raster(
    const float4* __restrict__ A_s, const float4* __restrict__ B_s,
    const float* __restrict__ C_s,
    const int* __restrict__ tile_list, const int* __restrict__ tile_cnt,
    float* __restrict__ img)
{
    int b = blockIdx.x;                    // 64 * 36 = 2304 blocks
    int tile = b / WAVES_PER_TILE;
    int sub  = b - tile * WAVES_PER_TILE;
    int lane = threadIdx.x & 63;
    int wv   = threadIdx.x >> 6;

    int idxp = sub * 4 + wv;               // 0..143 within tile
    int lx = idxp % TILE_PX, ly = idxp / TILE_PX;
    int tx = tile & (TILES_X - 1), ty = tile >> 3;
    int pxi = tx * TILE_PX + lx, pyi = ty * TILE_PX + ly;
    float px = (float)pxi, py = (float)pyi;
    int p = pyi * IMG_W + pxi;

    int cnt = tile_cnt[tile];
    const int* list = tile_list + tile * GS_N;

    float carry = 1.0f;
    float accr = 0.0f, accg = 0.0f, accb = 0.0f;

    for (int c0 = 0; c0 < cnt; c0 += 64) {
        int k = c0 + lane;
        float ap = 0.0f, colr = 0.0f, colg = 0.0f, colb = 0.0f;
        if (k < cnt) {
            int n = list[k];
            float4 a4 = A_s[n];
            float4 b4 = B_s[n];
            colb = C_s[n];
            colr = b4.z; colg = b4.w;

            float ddx = a4.x - px;
            float ddy = a4.y - py;
            float pw = -0.5f * (a4.z * ddx * ddx + b4.x * ddy * ddy) - a4.w * ddx * ddy;
            pw = fminf(pw, 0.0f);
            ap = b4.y * __expf(pw);
            ap = fminf(ap, 0.99f);
            ap = (ap >= (1.0f / 255.0f)) ? ap : 0.0f;
        }

        float f = 1.0f - ap;
        // inclusive prefix product across 64 lanes (Hillis-Steele)
        float incl = f;
        #pragma unroll
        for (int d = 1; d < 64; d <<= 1) {
            float v = __shfl_up(incl, d, 64);
            if (lane >= d) incl *= v;
        }
        float excl = __shfl_up(incl, 1, 64);
        if (lane == 0) excl = 1.0f;

        float tau = carry * excl;
        float wgt = (tau > 1e-4f) ? ap * tau : 0.0f;
        accr += colr * wgt;
        accg += colg * wgt;
        accb += colb * wgt;

        carry *= __shfl(incl, 63, 64);       // wave-uniform chunk transmittance
        if (carry <= 1e-4f) break;           // exact early exit (factors <= 1)
    }

    // wave reduction of the three accumulators
    #pragma unroll
    for (int d = 32; d >= 1; d >>= 1) {
        accr += __shfl_xor(accr, d, 64);
        accg += __shfl_xor(accg, d, 64);
        accb += __shfl_xor(accb, d, 64);
    }
    if (lane == 0) {
        img[0 * NPIX + p] = accr;
        img[1 * NPIX + p] = accg;
        img[2 * NPIX + p] = accb;
    }
}

extern "C" void kernel_launch(void* const* d_in, const int* in_sizes, int n_in,
                              void* d_out, int out_size, void* d_ws, size_t ws_size,
                              hipStream_t stream) {
    const float* pws        = (const float*)d_in[0];
    const float* low_shs    = (const float*)d_in[1];
    const float* high_shs   = (const float*)d_in[2];
    const float* alphas_raw = (const float*)d_in[3];
    const float* scales_raw = (const float*)d_in[4];
    const float* rots_raw   = (const float*)d_in[5];
    // d_in[6] = us (unused by the forward pass)
    const float* Rcw        = (const float*)d_in[7];
    const float* tcw        = (const float*)d_in[8];
    const float* cam        = (const float*)d_in[9];

    float* out_img   = (float*)d_out;             // 3*96*96
    float* out_areas = (float*)d_out + 3 * NPIX;  // N*2

    // workspace layout (bytes); ws_size is 256 MB — we use ~1.5 MB
    char* ws = (char*)d_ws;
    float*  depth_ws = (float*) (ws + 0);          // 16 KB
    int*    rank_ws  = (int*)   (ws + 16384);      // 16 KB
    float4* A_uns    = (float4*)(ws + 32768);      // 64 KB
    float4* B_uns    = (float4*)(ws + 98304);      // 64 KB
    float*  C_uns    = (float*) (ws + 163840);     // 16 KB
    float4* D_uns    = (float4*)(ws + 180224);     // 64 KB
    float4* A_s      = (float4*)(ws + 245760);     // 64 KB
    float4* B_s      = (float4*)(ws + 311296);     // 64 KB
    float*  C_s      = (float*) (ws + 376832);     // 16 KB
    float4* D_s      = (float4*)(ws + 393216);     // 64 KB
    int*    tile_cnt = (int*)   (ws + 458752);     // 256 B
    int*    tile_list= (int*)   (ws + 460800);     // 64*4096*4 = 1 MB

    gs_prep<<<GS_N / 256, 256, 0, stream>>>(
        pws, low_shs, high_shs, alphas_raw, scales_raw, rots_raw, Rcw, tcw, cam,
        out_areas, depth_ws, rank_ws, A_uns, B_uns, C_uns, D_uns);

    gs_rank_partial<<<256, 256, 0, stream>>>(depth_ws, rank_ws);

    gs_gather<<<GS_N / 256, 256, 0, stream>>>(
        rank_ws, A_uns, B_uns, C_uns, D_uns, A_s, B_s, C_s, D_s);

    gs_bin<<<NTILES, 256, 0, stream>>>(D_s, tile_list, tile_cnt);

    gs_raster<<<NTILES * WAVES_PER_TILE, 256, 0, stream>>>(
        A_s, B_s, C_s, tile_list, tile_cnt, out_img);
}